// Round 2
// baseline (532.197 us; speedup 1.0000x reference)
//
#include <hip/hip_runtime.h>
#include <hip/hip_bf16.h>
#include <stdint.h>

// out = x @ (sum_e w1[e] @ w2[e])   -- reassociated two-einsum.
// GEMM1: W[h][h2] += w1[e][h][:] . w2t[e][h2][:]   (split-K z=16, fp32 atomics)
// GEMM2: out = x @ W (via Wt bf16)
// LDS layout uses XOR swizzle: 16B granule g at row r lives at ((g + (r>>1)) & 3).
// Frag read for row R, quad lq reads granule slot ((lq + (R>>1)) & 3) -> bank-ideal.

#define BN 128
#define BK 32

typedef __attribute__((ext_vector_type(8))) short short8;
typedef __attribute__((ext_vector_type(4))) float float4v;
typedef __attribute__((ext_vector_type(4))) unsigned int uint4v;

__device__ __forceinline__ unsigned int rne_hi(unsigned int u) {
  return u + 0x7fffu + ((u >> 16) & 1u);
}

__device__ __forceinline__ unsigned int pack_bf16(float lo, float hi) {
  unsigned int ulo = rne_hi(__float_as_uint(lo));
  unsigned int uhi = rne_hi(__float_as_uint(hi));
  return __builtin_amdgcn_perm(uhi, ulo, 0x07060302u);
}

__device__ __forceinline__ void load_lds_16B(const void* g, void* lds) {
  __builtin_amdgcn_global_load_lds(
      (__attribute__((address_space(1))) void*)(uintptr_t)g,
      (__attribute__((address_space(3))) void*)(unsigned int)(uintptr_t)lds,
      16, 0, 0);
}

// C[M][N](fp32) (+)= A(fp32,[m][k],lda) * Bt(bf16,[n][k],ldb)^T
// BM = MI*32 (2 wave-rows of MI*16). BN=128 fixed (2 wave-cols of 64).
// blockIdx.z = zb*zdiv + zk: adds zb*stride + zk*K to both A and Bt k-offset.
template <int MI, bool ATOMIC>
__global__ __launch_bounds__(256) void gemm_f32a_bf16bt(
    const float* __restrict__ A, int lda, long strideA,
    const unsigned short* __restrict__ Bt, int ldb, long strideB,
    float* __restrict__ C, int ldc, int K, int zdiv) {
  constexpr int BM = MI * 32;
  __shared__ unsigned short As[BM * BK];  // swizzled [m][k], 64B rows
  __shared__ unsigned short Bs[BN * BK];  // swizzled [n][k], 64B rows

  const int tid = threadIdx.x;
  const int wv = tid >> 6;
  const int ln = tid & 63;
  const int wm = (wv >> 1) * (MI * 16);
  const int wn = (wv & 1) * 64;
  const int lrow = ln & 15;
  const int lq = ln >> 4;
  // swizzle slot for frag reads: rows are base(mult of 16)+lrow -> (R>>1)&3 == (lrow>>1)&3
  const int sfrag = ((lq + (lrow >> 1)) & 3) * 16;

  const int zb = blockIdx.z / zdiv;
  const int zk = blockIdx.z % zdiv;
  const float* Ab = A + (long)zb * strideA + (long)zk * K +
                    (long)(blockIdx.y * BM) * lda;
  const unsigned short* Bb = Bt + (long)zb * strideB + (long)zk * K +
                             (long)(blockIdx.x * BN) * ldb;

  float4v zero4 = {0.0f, 0.0f, 0.0f, 0.0f};
  float4v acc[MI][4];
#pragma unroll
  for (int i = 0; i < MI; ++i)
#pragma unroll
    for (int j = 0; j < 4; ++j) acc[i][j] = zero4;

  const int nk = K / BK;
  for (int kt = 0; kt < nk; ++kt) {
    const int k0 = kt * BK;
    __syncthreads();  // WAR: prev iter's frag reads done before restage
    // ---- stage A: fp32 global -> cvt bf16 -> swizzled ds_write_b128 ----
#pragma unroll
    for (int p = 0; p < BM / 64; ++p) {
      int o = p * 256 + tid;   // 16B-oct index
      int r = o >> 2;          // row
      int gk = o & 3;          // logical k-granule (8 elems)
      const float* g = Ab + (long)r * lda + k0 + gk * 8;
      float4 v0 = *(const float4*)g;
      float4 v1 = *(const float4*)(g + 4);
      uint4v d;
      d.x = pack_bf16(v0.x, v0.y);
      d.y = pack_bf16(v0.z, v0.w);
      d.z = pack_bf16(v1.x, v1.y);
      d.w = pack_bf16(v1.z, v1.w);
      int phys = r * 64 + (((gk + (r >> 1)) & 3) * 16);
      *(uint4v*)((char*)As + phys) = d;
    }
    // ---- stage B: bf16 global -> LDS direct; inverse-swizzle the SOURCE ----
#pragma unroll
    for (int p = 0; p < 2; ++p) {
      int o = p * 256 + wv * 64 + ln;  // phys 16B slot this lane fills
      int r = o >> 2;
      int gp = o & 3;                   // phys granule
      int gk = (gp - (r >> 1)) & 3;     // logical granule to fetch
      const unsigned short* g = Bb + (long)r * ldb + k0 + gk * 8;
      char* lp = (char*)Bs + (p * 256 + wv * 64) * 16;  // wave-uniform base
      load_lds_16B(g, lp);
    }
    __syncthreads();  // RAW: staging drained

    short8 a[MI], b[4];
#pragma unroll
    for (int i = 0; i < MI; ++i)
      a[i] = *(const short8*)((const char*)As + (wm + i * 16 + lrow) * 64 + sfrag);
#pragma unroll
    for (int j = 0; j < 4; ++j)
      b[j] = *(const short8*)((const char*)Bs + (wn + j * 16 + lrow) * 64 + sfrag);
#pragma unroll
    for (int i = 0; i < MI; ++i)
#pragma unroll
      for (int j = 0; j < 4; ++j)
        acc[i][j] = __builtin_amdgcn_mfma_f32_16x16x32_bf16(a[i], b[j], acc[i][j], 0, 0, 0);
  }

  // epilogue: C/D layout col=lane&15, row=(lane>>4)*4+reg
  const int crow0 = blockIdx.y * BM + wm + lq * 4;
  const int ccol0 = blockIdx.x * BN + wn + lrow;
#pragma unroll
  for (int i = 0; i < MI; ++i)
#pragma unroll
    for (int j = 0; j < 4; ++j)
#pragma unroll
      for (int r = 0; r < 4; ++r) {
        int row = crow0 + i * 16 + r;
        int col = ccol0 + j * 16;
        if (ATOMIC)
          atomicAdd(&C[(long)row * ldc + col], acc[i][j][r]);
        else
          C[(long)row * ldc + col] = acc[i][j][r];
      }
}

// in: fp32 [z][R][C]  ->  out: bf16 [z][C][R]   (64x64 LDS tile transpose + cvt)
__global__ __launch_bounds__(256) void transpose_cvt_kernel(
    const float* __restrict__ in, unsigned short* __restrict__ out,
    int R, int C, long strideBatch) {
  __shared__ float tile[64][65];
  const float* src = in + (long)blockIdx.z * strideBatch;
  unsigned short* dst = out + (long)blockIdx.z * strideBatch;
  const int t = threadIdx.x;
  const int c4 = (t & 15) * 4;
  const int r0 = t >> 4;
  const int by = blockIdx.y * 64;  // R offset
  const int bx = blockIdx.x * 64;  // C offset
#pragma unroll
  for (int p = 0; p < 4; ++p) {
    int r = r0 + p * 16;
    float4 v = *(const float4*)(src + (long)(by + r) * C + bx + c4);
    tile[r][c4 + 0] = v.x;
    tile[r][c4 + 1] = v.y;
    tile[r][c4 + 2] = v.z;
    tile[r][c4 + 3] = v.w;
  }
  __syncthreads();
#pragma unroll
  for (int p = 0; p < 4; ++p) {
    int cc = r0 + p * 16;  // out-row (C dim) within tile
    int rr = c4;           // out-col (R dim) within tile
    unsigned int d0 = pack_bf16(tile[rr + 0][cc], tile[rr + 1][cc]);
    unsigned int d1 = pack_bf16(tile[rr + 2][cc], tile[rr + 3][cc]);
    uint2 dd;
    dd.x = d0;
    dd.y = d1;
    *(uint2*)(dst + (long)(bx + cc) * R + by + rr) = dd;
  }
}

extern "C" void kernel_launch(void* const* d_in, const int* in_sizes, int n_in,
                              void* d_out, int out_size, void* d_ws, size_t ws_size,
                              hipStream_t stream) {
  const float* x = (const float*)d_in[0];   // [4,1024,1024]
  const float* w1 = (const float*)d_in[1];  // [8,1024,4096]
  const float* w2 = (const float*)d_in[2];  // [8,4096,1024]
  float* out = (float*)d_out;               // [4,1024,1024]

  const int A_ = 4, M_ = 1024, H_ = 1024, E_ = 8, N_ = 4096;

  // ws layout: w2t bf16 (67.1MB) | Wacc f32 (4.2MB) | Wt bf16 (2.1MB)
  unsigned short* w2t = (unsigned short*)d_ws;
  float* Wacc = (float*)((char*)d_ws + (size_t)E_ * H_ * N_ * 2);
  unsigned short* Wt = (unsigned short*)((char*)Wacc + (size_t)H_ * H_ * 4);

  // 1) w2 [E][N][H] -> w2t [E][H][N] (bf16)
  transpose_cvt_kernel<<<dim3(H_ / 64, N_ / 64, E_), 256, 0, stream>>>(
      w2, w2t, N_, H_, (long)N_ * H_);

  // 2) zero the W accumulator
  hipMemsetAsync(Wacc, 0, (size_t)H_ * H_ * 4, stream);

  // 3) GEMM1: W += w1[e] @ w2[e]  (split-K z=16: 2 chunks of 2048 per expert)
  gemm_f32a_bf16bt<4, true><<<dim3(H_ / BN, H_ / 128, E_ * 2), 256, 0, stream>>>(
      w1, N_, (long)H_ * N_, w2t, N_, (long)H_ * N_, Wacc, H_, 2048, 2);

  // 4) W f32 [H][H] -> Wt bf16 [H][H]^T
  transpose_cvt_kernel<<<dim3(H_ / 64, H_ / 64, 1), 256, 0, stream>>>(
      Wacc, Wt, H_, H_, 0);

  // 5) GEMM2: out = x @ W   (BM=64 tiles -> 512 blocks for occupancy)
  gemm_f32a_bf16bt<2, false><<<dim3(H_ / BN, (A_ * M_) / 64, 1), 256, 0, stream>>>(
      x, H_, 0, Wt, H_, 0, out, H_, 1024, 1);
}

// Round 3
// 488.017 us; speedup vs baseline: 1.0905x; 1.0905x over previous
//
#include <hip/hip_runtime.h>
#include <hip/hip_bf16.h>
#include <stdint.h>

// out = x @ (sum_e w1[e] @ w2[e])   -- reassociated two-einsum.
// GEMM1 computes W^T[h2][h] = sum_e,k w2t[e][h2][k] * w1[e][h][k]  (A=w2t, Bt=w1,
//   both bf16, both staged via global_load_lds width-16 -> m97 structure).
// W^T is exactly the Bt layout GEMM2 wants: out[m][h2] = sum_h xb[m][h] * Wt[h2][h].
// Experts processed in 2 groups of 4 to bound ws at ~82 MB.
// LDS XOR swizzle (verified 0 bank conflicts in R2): granule g of row r at ((g+(r>>1))&3).

#define BN 128
#define BK 32

typedef __attribute__((ext_vector_type(8))) short short8;
typedef __attribute__((ext_vector_type(4))) float float4v;
typedef __attribute__((ext_vector_type(4))) unsigned int uint4v;

__device__ __forceinline__ unsigned int rne_hi(unsigned int u) {
  return u + 0x7fffu + ((u >> 16) & 1u);
}

__device__ __forceinline__ unsigned int pack_bf16(float lo, float hi) {
  unsigned int ulo = rne_hi(__float_as_uint(lo));
  unsigned int uhi = rne_hi(__float_as_uint(hi));
  return __builtin_amdgcn_perm(uhi, ulo, 0x07060302u);
}

__device__ __forceinline__ void load_lds_16B(const void* g, void* lds) {
  __builtin_amdgcn_global_load_lds(
      (__attribute__((address_space(1))) void*)(uintptr_t)g,
      (__attribute__((address_space(3))) void*)(unsigned int)(uintptr_t)lds,
      16, 0, 0);
}

// C[M][N](fp32) (+)= A(bf16,[m][k],lda) * Bt(bf16,[n][k],ldb)^T
// BM = MI*32. BN=128. blockIdx.z = zb*zdiv + zk (zb: batch/expert, zk: K-chunk).
template <int MI, bool ATOMIC>
__global__ __launch_bounds__(256) void gemm_bf16(
    const unsigned short* __restrict__ A, int lda, long strideA,
    const unsigned short* __restrict__ Bt, int ldb, long strideB,
    float* __restrict__ C, int ldc, int K, int zdiv) {
  constexpr int BM = MI * 32;
  __shared__ __attribute__((aligned(16))) unsigned short As[BM * BK];
  __shared__ __attribute__((aligned(16))) unsigned short Bs[BN * BK];

  const int tid = threadIdx.x;
  const int wv = tid >> 6;
  const int ln = tid & 63;
  const int wm = (wv >> 1) * (MI * 16);
  const int wn = (wv & 1) * 64;
  const int lrow = ln & 15;
  const int lq = ln >> 4;
  const int sfrag = ((lq + (lrow >> 1)) & 3) * 16;  // swizzled frag granule

  const int zb = blockIdx.z / zdiv;
  const int zk = blockIdx.z % zdiv;
  const unsigned short* Ab = A + (long)zb * strideA + (long)zk * K +
                             (long)(blockIdx.y * BM) * lda;
  const unsigned short* Bb = Bt + (long)zb * strideB + (long)zk * K +
                             (long)(blockIdx.x * BN) * ldb;

  float4v zero4 = {0.0f, 0.0f, 0.0f, 0.0f};
  float4v acc[MI][4];
#pragma unroll
  for (int i = 0; i < MI; ++i)
#pragma unroll
    for (int j = 0; j < 4; ++j) acc[i][j] = zero4;

  const int nk = K / BK;
  for (int kt = 0; kt < nk; ++kt) {
    const int k0 = kt * BK;
    __syncthreads();  // WAR: prev iter's frag reads done before restage
    // ---- stage A: bf16 global -> LDS direct; inverse-swizzle the SOURCE ----
#pragma unroll
    for (int p = 0; p < BM / 64; ++p) {
      int o = p * 256 + wv * 64 + ln;   // phys 16B slot this lane fills
      int r = o >> 2;
      int gk = ((o & 3) - (r >> 1)) & 3;  // logical k-granule to fetch
      const unsigned short* g = Ab + (long)r * lda + k0 + gk * 8;
      char* lp = (char*)As + (p * 256 + wv * 64) * 16;  // wave-uniform base
      load_lds_16B(g, lp);
    }
    // ---- stage B: same scheme ----
#pragma unroll
    for (int p = 0; p < 2; ++p) {
      int o = p * 256 + wv * 64 + ln;
      int r = o >> 2;
      int gk = ((o & 3) - (r >> 1)) & 3;
      const unsigned short* g = Bb + (long)r * ldb + k0 + gk * 8;
      char* lp = (char*)Bs + (p * 256 + wv * 64) * 16;
      load_lds_16B(g, lp);
    }
    __syncthreads();  // RAW: staging drained

    short8 a[MI], b[4];
#pragma unroll
    for (int i = 0; i < MI; ++i)
      a[i] = *(const short8*)((const char*)As + (wm + i * 16 + lrow) * 64 + sfrag);
#pragma unroll
    for (int j = 0; j < 4; ++j)
      b[j] = *(const short8*)((const char*)Bs + (wn + j * 16 + lrow) * 64 + sfrag);
#pragma unroll
    for (int i = 0; i < MI; ++i)
#pragma unroll
      for (int j = 0; j < 4; ++j)
        acc[i][j] = __builtin_amdgcn_mfma_f32_16x16x32_bf16(a[i], b[j], acc[i][j], 0, 0, 0);
  }

  // epilogue: C/D layout col=lane&15, row=(lane>>4)*4+reg
  const int crow0 = blockIdx.y * BM + wm + lq * 4;
  const int ccol0 = blockIdx.x * BN + wn + lrow;
#pragma unroll
  for (int i = 0; i < MI; ++i)
#pragma unroll
    for (int j = 0; j < 4; ++j)
#pragma unroll
      for (int r = 0; r < 4; ++r) {
        int row = crow0 + i * 16 + r;
        int col = ccol0 + j * 16;
        if (ATOMIC)
          atomicAdd(&C[(long)row * ldc + col], acc[i][j][r]);
        else
          C[(long)row * ldc + col] = acc[i][j][r];
      }
}

// elementwise fp32 -> bf16, 8 elems/thread, exact grid (n % 2048 == 0)
__global__ __launch_bounds__(256) void cvt_f32_bf16(
    const float* __restrict__ in, unsigned short* __restrict__ out) {
  long i = ((long)blockIdx.x * 256 + threadIdx.x) * 8;
  float4 v0 = *(const float4*)(in + i);
  float4 v1 = *(const float4*)(in + i + 4);
  uint4v d;
  d.x = pack_bf16(v0.x, v0.y);
  d.y = pack_bf16(v0.z, v0.w);
  d.z = pack_bf16(v1.x, v1.y);
  d.w = pack_bf16(v1.z, v1.w);
  *(uint4v*)(out + i) = d;
}

// in: fp32 [z][R][C] -> out: bf16 [z][C][R]   (64x64 LDS tile transpose + cvt)
__global__ __launch_bounds__(256) void transpose_cvt_kernel(
    const float* __restrict__ in, unsigned short* __restrict__ out,
    int R, int C, long strideBatch) {
  __shared__ float tile[64][65];
  const float* src = in + (long)blockIdx.z * strideBatch;
  unsigned short* dst = out + (long)blockIdx.z * strideBatch;
  const int t = threadIdx.x;
  const int c4 = (t & 15) * 4;
  const int r0 = t >> 4;
  const int by = blockIdx.y * 64;  // R offset
  const int bx = blockIdx.x * 64;  // C offset
#pragma unroll
  for (int p = 0; p < 4; ++p) {
    int r = r0 + p * 16;
    float4 v = *(const float4*)(src + (long)(by + r) * C + bx + c4);
    tile[r][c4 + 0] = v.x;
    tile[r][c4 + 1] = v.y;
    tile[r][c4 + 2] = v.z;
    tile[r][c4 + 3] = v.w;
  }
  __syncthreads();
#pragma unroll
  for (int p = 0; p < 4; ++p) {
    int cc = r0 + p * 16;
    int rr = c4;
    unsigned int d0 = pack_bf16(tile[rr + 0][cc], tile[rr + 1][cc]);
    unsigned int d1 = pack_bf16(tile[rr + 2][cc], tile[rr + 3][cc]);
    uint2 dd;
    dd.x = d0;
    dd.y = d1;
    *(uint2*)(dst + (long)(bx + cc) * R + by + rr) = dd;
  }
}

extern "C" void kernel_launch(void* const* d_in, const int* in_sizes, int n_in,
                              void* d_out, int out_size, void* d_ws, size_t ws_size,
                              hipStream_t stream) {
  const float* x = (const float*)d_in[0];   // [4,1024,1024]
  const float* w1 = (const float*)d_in[1];  // [8,1024,4096]
  const float* w2 = (const float*)d_in[2];  // [8,4096,1024]
  float* out = (float*)d_out;               // [4,1024,1024]

  const int A_ = 4, M_ = 1024, H_ = 1024, E_ = 8, N_ = 4096;
  const long EXP = (long)H_ * N_;  // 4.19M elems per expert

  // ws layout (group of 4 experts at a time):
  //   w2t bf16 [4][H][N] 33.5MB | w1b bf16 [4][H][N] 33.5MB | xb bf16 8.4MB |
  //   Wacc f32 [H][H] 4.2MB | Wb bf16 [H][H] 2.1MB      total ~81.7MB
  unsigned short* w2t = (unsigned short*)d_ws;
  unsigned short* w1b = w2t + 4 * EXP;
  unsigned short* xb = w1b + 4 * EXP;
  float* Wacc = (float*)(xb + (long)A_ * M_ * H_);
  unsigned short* Wb = (unsigned short*)(Wacc + (long)H_ * H_);

  // x -> bf16 (independent of the groups)
  cvt_f32_bf16<<<(A_ * M_ * H_) / 2048, 256, 0, stream>>>(x, xb);
  // zero the W^T accumulator
  hipMemsetAsync(Wacc, 0, (size_t)H_ * H_ * 4, stream);

  for (int g = 0; g < 2; ++g) {
    const float* w2g = w2 + (long)g * 4 * EXP;
    const float* w1g = w1 + (long)g * 4 * EXP;
    // w2[group] [4][N][H] -> w2t [4][H][N] bf16
    transpose_cvt_kernel<<<dim3(H_ / 64, N_ / 64, 4), 256, 0, stream>>>(
        w2g, w2t, N_, H_, EXP);
    // w1[group] -> bf16 (same layout)
    cvt_f32_bf16<<<(int)(4 * EXP / 2048), 256, 0, stream>>>(w1g, w1b);
    // W^T[h2][h] += w2t[e] @ w1[e]^T   (split-K: 2 chunks of 2048 per expert)
    gemm_bf16<4, true><<<dim3(H_ / BN, H_ / 128, 4 * 2), 256, 0, stream>>>(
        w2t, N_, EXP, w1b, N_, EXP, Wacc, H_, N_ / 2, 2);
  }

  // W^T f32 -> bf16 (no transpose needed; it's already Bt layout for GEMM2)
  cvt_f32_bf16<<<(H_ * H_) / 2048, 256, 0, stream>>>(Wacc, Wb);

  // GEMM2: out = xb @ W   (A=xb [m][h], Bt=Wb=W^T [h2][h]); BM=64 -> 512 blocks
  gemm_bf16<2, false><<<dim3(H_ / BN, (A_ * M_) / 64, 1), 256, 0, stream>>>(
      xb, H_, 0, Wb, H_, 0, out, H_, H_, 1);
}

// Round 4
// 469.853 us; speedup vs baseline: 1.1327x; 1.0387x over previous
//
#include <hip/hip_runtime.h>
#include <hip/hip_bf16.h>
#include <stdint.h>

// out = x @ (sum_e w1[e] @ w2[e])   -- reassociated two-einsum.
// GEMM1: W^T[h2][h] = sum_e,k w2t[e][h2][k] * w1[e][h][k]  (A=w2t, Bt=w1, both bf16,
//   both staged via global_load_lds width-16; BK=64 as two 32-wide sub-buffers).
// W^T is exactly the Bt layout GEMM2 wants.
// LDS XOR swizzle (0 conflicts verified R2/R3): granule g of row r at ((g+(r>>1))&3).
// Single-shot (all 8 experts, ws >= ~149MB) with a proven 2-group fallback.

#define BN 128

typedef __attribute__((ext_vector_type(8))) short short8;
typedef __attribute__((ext_vector_type(4))) float float4v;
typedef __attribute__((ext_vector_type(4))) unsigned int uint4v;

__device__ __forceinline__ unsigned int rne_hi(unsigned int u) {
  return u + 0x7fffu + ((u >> 16) & 1u);
}

__device__ __forceinline__ unsigned int pack_bf16(float lo, float hi) {
  unsigned int ulo = rne_hi(__float_as_uint(lo));
  unsigned int uhi = rne_hi(__float_as_uint(hi));
  return __builtin_amdgcn_perm(uhi, ulo, 0x07060302u);
}

__device__ __forceinline__ void load_lds_16B(const void* g, void* lds) {
  __builtin_amdgcn_global_load_lds(
      (__attribute__((address_space(1))) void*)(uintptr_t)g,
      (__attribute__((address_space(3))) void*)(unsigned int)(uintptr_t)lds,
      16, 0, 0);
}

// C[M][N](fp32) (+)= A(bf16,[m][k],lda) * Bt(bf16,[n][k],ldb)^T
// BM = MI*32. BN=128. blockIdx.z = zb*zdiv + zk (zb: batch index, zk: K-chunk).
// K-loop: BK=64 as two BK=32 sub-stages per barrier pair (32 MFMA per drain).
template <int MI, bool ATOMIC>
__global__ __launch_bounds__(256) void gemm_bf16(
    const unsigned short* __restrict__ A, int lda, long strideA,
    const unsigned short* __restrict__ Bt, int ldb, long strideB,
    float* __restrict__ C, int ldc, int K, int zdiv) {
  constexpr int BM = MI * 32;
  __shared__ __attribute__((aligned(16))) unsigned short As[2 * BM * 32];
  __shared__ __attribute__((aligned(16))) unsigned short Bs[2 * BN * 32];

  const int tid = threadIdx.x;
  const int wv = tid >> 6;
  const int ln = tid & 63;
  const int wm = (wv >> 1) * (MI * 16);
  const int wn = (wv & 1) * 64;
  const int lrow = ln & 15;
  const int lq = ln >> 4;
  const int sfrag = ((lq + (lrow >> 1)) & 3) * 16;  // swizzled frag granule

  const int zb = blockIdx.z / zdiv;
  const int zk = blockIdx.z % zdiv;
  const unsigned short* Ab = A + (long)zb * strideA + (long)zk * K +
                             (long)(blockIdx.y * BM) * lda;
  const unsigned short* Bb = Bt + (long)zb * strideB + (long)zk * K +
                             (long)(blockIdx.x * BN) * ldb;

  float4v zero4 = {0.0f, 0.0f, 0.0f, 0.0f};
  float4v acc[MI][4];
#pragma unroll
  for (int i = 0; i < MI; ++i)
#pragma unroll
    for (int j = 0; j < 4; ++j) acc[i][j] = zero4;

  const int nk = K / 64;
  for (int kt = 0; kt < nk; ++kt) {
    const int k0 = kt * 64;
    __syncthreads();  // WAR: prev iter's frag reads done before restage
#pragma unroll
    for (int s = 0; s < 2; ++s) {
      // ---- stage A sub s: bf16 global -> LDS direct; inverse-swizzle SOURCE ----
#pragma unroll
      for (int p = 0; p < BM / 64; ++p) {
        int o = p * 256 + wv * 64 + ln;     // phys 16B slot within sub
        int r = o >> 2;
        int gk = ((o & 3) - (r >> 1)) & 3;  // logical k-granule to fetch
        const unsigned short* g = Ab + (long)r * lda + k0 + s * 32 + gk * 8;
        char* lp = (char*)As + s * (BM * 64) + (p * 256 + wv * 64) * 16;
        load_lds_16B(g, lp);
      }
      // ---- stage B sub s ----
#pragma unroll
      for (int p = 0; p < 2; ++p) {
        int o = p * 256 + wv * 64 + ln;
        int r = o >> 2;
        int gk = ((o & 3) - (r >> 1)) & 3;
        const unsigned short* g = Bb + (long)r * ldb + k0 + s * 32 + gk * 8;
        char* lp = (char*)Bs + s * (BN * 64) + (p * 256 + wv * 64) * 16;
        load_lds_16B(g, lp);
      }
    }
    __syncthreads();  // RAW: staging drained

#pragma unroll
    for (int s = 0; s < 2; ++s) {
      short8 a[MI], b[4];
#pragma unroll
      for (int i = 0; i < MI; ++i)
        a[i] = *(const short8*)((const char*)As + s * (BM * 64) +
                                (wm + i * 16 + lrow) * 64 + sfrag);
#pragma unroll
      for (int j = 0; j < 4; ++j)
        b[j] = *(const short8*)((const char*)Bs + s * (BN * 64) +
                                (wn + j * 16 + lrow) * 64 + sfrag);
#pragma unroll
      for (int i = 0; i < MI; ++i)
#pragma unroll
        for (int j = 0; j < 4; ++j)
          acc[i][j] =
              __builtin_amdgcn_mfma_f32_16x16x32_bf16(a[i], b[j], acc[i][j], 0, 0, 0);
    }
  }

  // epilogue: C/D layout col=lane&15, row=(lane>>4)*4+reg
  const int crow0 = blockIdx.y * BM + wm + lq * 4;
  const int ccol0 = blockIdx.x * BN + wn + lrow;
#pragma unroll
  for (int i = 0; i < MI; ++i)
#pragma unroll
    for (int j = 0; j < 4; ++j)
#pragma unroll
      for (int r = 0; r < 4; ++r) {
        int row = crow0 + i * 16 + r;
        int col = ccol0 + j * 16;
        if (ATOMIC)
          atomicAdd(&C[(long)row * ldc + col], acc[i][j][r]);
        else
          C[(long)row * ldc + col] = acc[i][j][r];
      }
}

// elementwise fp32 -> bf16, 8 elems/thread, exact grid (n % 2048 == 0)
__global__ __launch_bounds__(256) void cvt_f32_bf16(
    const float* __restrict__ in, unsigned short* __restrict__ out) {
  long i = ((long)blockIdx.x * 256 + threadIdx.x) * 8;
  float4 v0 = *(const float4*)(in + i);
  float4 v1 = *(const float4*)(in + i + 4);
  uint4v d;
  d.x = pack_bf16(v0.x, v0.y);
  d.y = pack_bf16(v0.z, v0.w);
  d.z = pack_bf16(v1.x, v1.y);
  d.w = pack_bf16(v1.z, v1.w);
  *(uint4v*)(out + i) = d;
}

// in: fp32 [z][R][C] -> out: bf16 [z][C][R]   (64x64 LDS tile transpose + cvt)
__global__ __launch_bounds__(256) void transpose_cvt_kernel(
    const float* __restrict__ in, unsigned short* __restrict__ out,
    int R, int C, long strideBatch) {
  __shared__ float tile[64][65];
  const float* src = in + (long)blockIdx.z * strideBatch;
  unsigned short* dst = out + (long)blockIdx.z * strideBatch;
  const int t = threadIdx.x;
  const int c4 = (t & 15) * 4;
  const int r0 = t >> 4;
  const int by = blockIdx.y * 64;  // R offset
  const int bx = blockIdx.x * 64;  // C offset
#pragma unroll
  for (int p = 0; p < 4; ++p) {
    int r = r0 + p * 16;
    float4 v = *(const float4*)(src + (long)(by + r) * C + bx + c4);
    tile[r][c4 + 0] = v.x;
    tile[r][c4 + 1] = v.y;
    tile[r][c4 + 2] = v.z;
    tile[r][c4 + 3] = v.w;
  }
  __syncthreads();
#pragma unroll
  for (int p = 0; p < 4; ++p) {
    int cc = r0 + p * 16;
    int rr = c4;
    unsigned int d0 = pack_bf16(tile[rr + 0][cc], tile[rr + 1][cc]);
    unsigned int d1 = pack_bf16(tile[rr + 2][cc], tile[rr + 3][cc]);
    uint2 dd;
    dd.x = d0;
    dd.y = d1;
    *(uint2*)(dst + (long)(bx + cc) * R + by + rr) = dd;
  }
}

extern "C" void kernel_launch(void* const* d_in, const int* in_sizes, int n_in,
                              void* d_out, int out_size, void* d_ws, size_t ws_size,
                              hipStream_t stream) {
  const float* x = (const float*)d_in[0];   // [4,1024,1024]
  const float* w1 = (const float*)d_in[1];  // [8,1024,4096]
  const float* w2 = (const float*)d_in[2];  // [8,4096,1024]
  float* out = (float*)d_out;               // [4,1024,1024]

  const int A_ = 4, M_ = 1024, H_ = 1024, E_ = 8, N_ = 4096;
  const long EXP = (long)H_ * N_;  // 4.19M elems per expert

  // single-shot ws need: w2t[8] 67.1MB + w1b[8] 67.1MB + xb 8.4MB + Wacc 4.2MB + Wb 2.1MB
  const size_t need_single =
      (size_t)2 * E_ * EXP * 2 + (size_t)A_ * M_ * H_ * 2 +
      (size_t)H_ * H_ * 4 + (size_t)H_ * H_ * 2;

  if (ws_size >= need_single) {
    // ---------------- single-shot path ----------------
    unsigned short* w2t = (unsigned short*)d_ws;
    unsigned short* w1b = w2t + (long)E_ * EXP;
    unsigned short* xb = w1b + (long)E_ * EXP;
    float* Wacc = (float*)(xb + (long)A_ * M_ * H_);
    unsigned short* Wb = (unsigned short*)(Wacc + (long)H_ * H_);

    cvt_f32_bf16<<<(A_ * M_ * H_) / 2048, 256, 0, stream>>>(x, xb);
    transpose_cvt_kernel<<<dim3(H_ / 64, N_ / 64, E_), 256, 0, stream>>>(
        w2, w2t, N_, H_, EXP);
    cvt_f32_bf16<<<(int)(E_ * EXP / 2048), 256, 0, stream>>>(w1, w1b);
    hipMemsetAsync(Wacc, 0, (size_t)H_ * H_ * 4, stream);

    // GEMM1: 8 experts x 2 K-chunks of 2048 -> 1024 blocks
    gemm_bf16<4, true><<<dim3(H_ / BN, H_ / 128, E_ * 2), 256, 0, stream>>>(
        w2t, N_, EXP, w1b, N_, EXP, Wacc, H_, N_ / 2, 2);

    cvt_f32_bf16<<<(H_ * H_) / 2048, 256, 0, stream>>>(Wacc, Wb);

    gemm_bf16<2, false><<<dim3(H_ / BN, (A_ * M_) / 64, 1), 256, 0, stream>>>(
        xb, H_, 0, Wb, H_, 0, out, H_, H_, 1);
  } else {
    // ---------------- 2-group fallback (proven at ~82MB) ----------------
    unsigned short* w2t = (unsigned short*)d_ws;
    unsigned short* w1b = w2t + 4 * EXP;
    unsigned short* xb = w1b + 4 * EXP;
    float* Wacc = (float*)(xb + (long)A_ * M_ * H_);
    unsigned short* Wb = (unsigned short*)(Wacc + (long)H_ * H_);

    cvt_f32_bf16<<<(A_ * M_ * H_) / 2048, 256, 0, stream>>>(x, xb);
    hipMemsetAsync(Wacc, 0, (size_t)H_ * H_ * 4, stream);

    for (int g = 0; g < 2; ++g) {
      const float* w2g = w2 + (long)g * 4 * EXP;
      const float* w1g = w1 + (long)g * 4 * EXP;
      transpose_cvt_kernel<<<dim3(H_ / 64, N_ / 64, 4), 256, 0, stream>>>(
          w2g, w2t, N_, H_, EXP);
      cvt_f32_bf16<<<(int)(4 * EXP / 2048), 256, 0, stream>>>(w1g, w1b);
      gemm_bf16<4, true><<<dim3(H_ / BN, H_ / 128, 4 * 2), 256, 0, stream>>>(
          w2t, N_, EXP, w1b, N_, EXP, Wacc, H_, N_ / 2, 2);
    }

    cvt_f32_bf16<<<(H_ * H_) / 2048, 256, 0, stream>>>(Wacc, Wb);
    gemm_bf16<2, false><<<dim3(H_ / BN, (A_ * M_) / 64, 1), 256, 0, stream>>>(
        xb, H_, 0, Wb, H_, 0, out, H_, H_, 1);
  }
}